// Round 2
// baseline (325.510 us; speedup 1.0000x reference)
//
#include <hip/hip_runtime.h>

#define HW 512
#define RA 0.35355339059327373f
#define RB 0.25f

typedef float fvec4 __attribute__((ext_vector_type(4)));

__device__ __forceinline__ int reflect512(int v) {
    v = v < 0 ? -v : v;
    v = v > 511 ? 1022 - v : v;
    return v;
}

__device__ __forceinline__ float softt2(float x) {
    // soft-threshold at lambda=0.1 (operates on 2x-scaled Haar values)
    return copysignf(fmaxf(fabsf(x) - 0.1f, 0.0f), x);
}

__device__ __forceinline__ float nlin(float t) {
    float ca = fabsf(t);
    t = (ca < 2.5f) ? t * (ca * 0.4f) : t;
    return fminf(fmaxf(t, -10.0f), 10.0f);
}

// Haar refine with the two 0.5 scales folded into one 0.25 at the end.
// softt(0.5*x) == 0.5*softt2(x) exactly (power-of-2 scaling commutes with rounding,
// and 0.05f is exactly 0.5*0.1f).
__device__ __forceinline__ void haar_quad(float a, float b, float c, float d,
                                          float& oa, float& ob, float& oc, float& od) {
    float s1 = a + b, s2 = c + d, d1 = a - b, d2 = c - d;
    float LL = s1 + s2, LH = s1 - s2, HL = d1 + d2, HH = d1 - d2;  // 2x scaled
    LH = softt2(LH); HL = softt2(HL); HH = softt2(HH);
    float u1 = LL + LH, u2 = HL + HH, w1 = LL - LH, w2 = HL - HH;
    oa = (u1 + u2) * 0.25f; ob = (u1 - u2) * 0.25f;
    oc = (w1 + w2) * 0.25f; od = (w1 - w2) * 0.25f;
}

// 8-pt cos-DFT, distinct outputs only (full: [t0,t1,t2,t3,t4,t3,t2,t1])
__device__ __forceinline__ void cos5(const float* __restrict__ x, float* __restrict__ t) {
    float e0 = x[0] + x[4], d0 = x[0] - x[4];
    float e1 = x[2] + x[6];
    float o0 = x[1] + x[5], m0 = x[1] - x[5];
    float o1 = x[3] + x[7], m1 = x[3] - x[7];
    float see = e0 + e1, dee = e0 - e1, soo = o0 + o1, dd = m0 - m1;
    t[0] = RA * (see + soo);
    t[4] = RA * (see - soo);
    t[2] = RA * dee;
    float a = RA * d0, b = RB * dd;
    t[1] = a + b;
    t[3] = a - b;
}

// 8-pt sin-DFT, distinct outputs only (full: [0,s0,s1,s2,0,-s2,-s1,-s0])
__device__ __forceinline__ void sin3(const float* __restrict__ x, float* __restrict__ s) {
    float d1 = x[2] - x[6];
    float m0 = x[1] - x[5];
    float o0 = x[1] + x[5];
    float o1 = x[3] + x[7], m1 = x[3] - x[7];
    float qq = m0 + m1;
    float a = RB * qq, b = RA * d1;
    s[0] = a + b;
    s[1] = RA * (o0 - o1);
    s[2] = a - b;
}

// cos-DFT of a symmetric 8-vector [x0,x1,x2,x3,x4,x3,x2,x1] (exact specialization)
__device__ __forceinline__ void cos5_sym(const float* __restrict__ x, float* __restrict__ t) {
    float e0 = x[0] + x[4], d0 = x[0] - x[4];
    float tx2 = 2.0f * x[2];
    float see = e0 + tx2, dee = e0 - tx2;
    float soo = 2.0f * (x[1] + x[3]);
    float m0 = x[1] - x[3];
    t[0] = RA * (see + soo);
    t[4] = RA * (see - soo);
    t[2] = RA * dee;
    float a = RA * d0, b = 0.5f * m0;   // RB * (2*m0)
    t[1] = a + b;
    t[3] = a - b;
}

// sin-DFT of an antisymmetric 8-vector [0,y0,y1,y2,0,-y2,-y1,-y0] (exact specialization)
__device__ __forceinline__ void sin3_asym(const float* __restrict__ y, float* __restrict__ s) {
    float a = 0.5f * (y[0] + y[2]);          // RB * (2*(y0+y2))
    float b = (2.0f * RA) * y[1];            // RA * (2*y1)
    s[0] = a + b;
    s[1] = (2.0f * RA) * (y[0] - y[2]);
    s[2] = a - b;
}

__device__ __forceinline__ void nt_store4(float* p, float a, float b, float c, float d) {
    fvec4 v = {a, b, c, d};
    __builtin_nontemporal_store(v, (fvec4*)p);
}

__launch_bounds__(256, 3)
__global__ void sas_fused(const float* __restrict__ in, float* __restrict__ out) {
    const int lane = threadIdx.x & 63;   // block-col 0..63
    const int wv = threadIdx.x >> 6;     // wave in workgroup
    const int p = blockIdx.y;            // plane (b*3+c)
    const int by = blockIdx.x * 4 + wv;  // block-row 0..63
    const float* __restrict__ inP = in + (size_t)p * (HW * HW);
    const int cx = lane * 8;

    const float e = 0.45783336f;                  // exp(-1/1.28)
    const float inv_s = 1.0f / ((1.0f + 2.0f * e) * (1.0f + 2.0f * e));

    // ---- streamed load + separable 3x3 gaussian (rolling 3-row h buffer) ----
    float B[8][8];
    float h[3][8];
#pragma unroll
    for (int j = 0; j < 10; ++j) {
        int gy = reflect512(by * 8 - 1 + j);
        const float* r = inP + (size_t)gy * HW + cx;
        float4 va = *(const float4*)r;
        float4 vb = *(const float4*)(r + 4);
        float lft = __shfl_up(vb.w, 1);    // neighbor's col 7
        float rgt = __shfl_down(va.x, 1);  // neighbor's col 0
        if (lane == 0)  lft = va.y;        // reflect(-1) = col 1
        if (lane == 63) rgt = vb.z;        // reflect(512) = col 510
        float xr[10] = {lft, va.x, va.y, va.z, va.w, vb.x, vb.y, vb.z, vb.w, rgt};
        float* hc = h[j % 3];
#pragma unroll
        for (int c = 0; c < 8; ++c)
            hc[c] = e * (xr[c] + xr[c + 2]) + xr[c + 1];
        if (j >= 2) {
            const float* h0 = h[(j - 2) % 3];
            const float* h1 = h[(j - 1) % 3];
#pragma unroll
            for (int c = 0; c < 8; ++c)
                B[j - 2][c] = (e * (h0[c] + hc[c]) + h1[c]) * inv_s;
        }
    }

    // ---- forward row pass: per row keep 5 cos + 3 sin distinct values (transposed) ----
    float cpT[5][8], spT[3][8];
#pragma unroll
    for (int m = 0; m < 8; ++m) {
        float t[5], s[3];
        cos5(B[m], t);
        sin3(B[m], s);
#pragma unroll
        for (int v = 0; v < 5; ++v) cpT[v][m] = t[v];
#pragma unroll
        for (int v = 0; v < 3; ++v) spT[v][m] = s[v];
    }

    // ---- forward column pass -> 34 distinct T values ----
    // T[u][v] = cosDFT(P col v)[u] - sinDFT(Q col v)[u]; cols 5..7 mirror 3..1 with +sin.
    float Tc0[5], Tc4[5];            // T[:,0], T[:,4] (u-symmetric, 5 distinct each)
    cos5(cpT[0], Tc0);
    cos5(cpT[4], Tc4);
    float Tt[3], Tb[3], TA[3][3], TB[3][3];  // per v=1..3: u=0, u=4, u=1..3 (-sin), u=1..3 (+sin)
#pragma unroll
    for (int vi = 0; vi < 3; ++vi) {
        float t[5], s[3];
        cos5(cpT[vi + 1], t);
        sin3(spT[vi], s);
        Tt[vi] = t[0];
        Tb[vi] = t[4];
#pragma unroll
        for (int ui = 0; ui < 3; ++ui) {
            TA[vi][ui] = t[ui + 1] - s[ui];
            TB[vi][ui] = t[ui + 1] + s[ui];
        }
    }

    // ---- nonlinearity on the 34 distinct values (duplicates stay exactly equal) ----
#pragma unroll
    for (int i = 0; i < 5; ++i) { Tc0[i] = nlin(Tc0[i]); Tc4[i] = nlin(Tc4[i]); }
#pragma unroll
    for (int vi = 0; vi < 3; ++vi) {
        Tt[vi] = nlin(Tt[vi]);
        Tb[vi] = nlin(Tb[vi]);
#pragma unroll
        for (int ui = 0; ui < 3; ++ui) {
            TA[vi][ui] = nlin(TA[vi][ui]);
            TB[vi][ui] = nlin(TB[vi][ui]);
        }
    }

    // ---- inverse row pass: rows 0,4 are symmetric; rows 5..7 mirror 3..1 ----
    float p2[5][5], q2[3][3];
    {
        float x0[5] = {Tc0[0], Tt[0], Tt[1], Tt[2], Tc4[0]};
        cos5_sym(x0, p2[0]);
        float x4[5] = {Tc0[4], Tb[0], Tb[1], Tb[2], Tc4[4]};
        cos5_sym(x4, p2[4]);
    }
#pragma unroll
    for (int u = 1; u <= 3; ++u) {
        float r8[8] = {Tc0[u], TA[0][u - 1], TA[1][u - 1], TA[2][u - 1], Tc4[u],
                       TB[2][u - 1], TB[1][u - 1], TB[0][u - 1]};
        cos5(r8, p2[u]);
        sin3(r8, q2[u - 1]);
    }

    // ---- inverse column pass: p2 cols symmetric, q2 cols antisymmetric ----
    float Rc0[5], Rc4[5];
    {
        float c0[5] = {p2[0][0], p2[1][0], p2[2][0], p2[3][0], p2[4][0]};
        cos5_sym(c0, Rc0);
        float c4[5] = {p2[0][4], p2[1][4], p2[2][4], p2[3][4], p2[4][4]};
        cos5_sym(c4, Rc4);
    }
    float r0v[3], r4v[3], RAm[3][3], RBm[3][3];
#pragma unroll
    for (int vi = 0; vi < 3; ++vi) {
        int v = vi + 1;
        float cs[5] = {p2[0][v], p2[1][v], p2[2][v], p2[3][v], p2[4][v]};
        float t[5];
        cos5_sym(cs, t);
        float y[3] = {q2[0][vi], q2[1][vi], q2[2][vi]};
        float s[3];
        sin3_asym(y, s);
        r0v[vi] = t[0];
        r4v[vi] = t[4];
#pragma unroll
        for (int ui = 0; ui < 3; ++ui) {
            RAm[vi][ui] = t[ui + 1] - s[ui];
            RBm[vi][ui] = t[ui + 1] + s[ui];
        }
    }

    // ---- expand rec (centro-symmetric) from 34 distinct values (register renames) ----
    float rec[8][8];
#pragma unroll
    for (int u = 0; u < 8; ++u) {
        int us = (u <= 4) ? u : 8 - u;
        rec[u][0] = Rc0[us];
        rec[u][4] = Rc4[us];
    }
#pragma unroll
    for (int v = 1; v < 8; ++v) {
        if (v == 4) continue;
        int vs = (v <= 4) ? v : 8 - v;
        bool vf = v > 4;
        rec[0][v] = r0v[vs - 1];
        rec[4][v] = r4v[vs - 1];
#pragma unroll
        for (int u = 1; u < 8; ++u) {
            if (u == 4) continue;
            int us = (u <= 4) ? u : 8 - u;
            bool uf = u > 4;
            rec[u][v] = (vf != uf) ? RBm[vs - 1][us - 1] : RAm[vs - 1][us - 1];
        }
    }

    // ---- residual + Haar refine on both streams + coalesced nontemporal stores ----
    const int chId = (p / 3) * 6 + (p % 3);
    float* __restrict__ oI = out + ((size_t)chId << 18);
    float* __restrict__ oR = out + ((size_t)(chId + 3) << 18);
#pragma unroll
    for (int qy = 0; qy < 4; ++qy) {
        float ti[2][8], tr_[2][8];
#pragma unroll
        for (int qx = 0; qx < 4; ++qx) {
            float d00 = rec[2 * qy][2 * qx],     d01 = rec[2 * qy][2 * qx + 1];
            float d10 = rec[2 * qy + 1][2 * qx], d11 = rec[2 * qy + 1][2 * qx + 1];
            haar_quad(d00, d01, d10, d11,
                      ti[0][2 * qx], ti[0][2 * qx + 1], ti[1][2 * qx], ti[1][2 * qx + 1]);
            float r00 = B[2 * qy][2 * qx]     - d00, r01 = B[2 * qy][2 * qx + 1]     - d01;
            float r10 = B[2 * qy + 1][2 * qx] - d10, r11 = B[2 * qy + 1][2 * qx + 1] - d11;
            haar_quad(r00, r01, r10, r11,
                      tr_[0][2 * qx], tr_[0][2 * qx + 1], tr_[1][2 * qx], tr_[1][2 * qx + 1]);
        }
        size_t base = (size_t)(by * 8 + 2 * qy) * HW + cx;
        nt_store4(&oI[base],          ti[0][0], ti[0][1], ti[0][2], ti[0][3]);
        nt_store4(&oI[base + 4],      ti[0][4], ti[0][5], ti[0][6], ti[0][7]);
        nt_store4(&oI[base + HW],     ti[1][0], ti[1][1], ti[1][2], ti[1][3]);
        nt_store4(&oI[base + HW + 4], ti[1][4], ti[1][5], ti[1][6], ti[1][7]);
        nt_store4(&oR[base],          tr_[0][0], tr_[0][1], tr_[0][2], tr_[0][3]);
        nt_store4(&oR[base + 4],      tr_[0][4], tr_[0][5], tr_[0][6], tr_[0][7]);
        nt_store4(&oR[base + HW],     tr_[1][0], tr_[1][1], tr_[1][2], tr_[1][3]);
        nt_store4(&oR[base + HW + 4], tr_[1][4], tr_[1][5], tr_[1][6], tr_[1][7]);
    }
}

extern "C" void kernel_launch(void* const* d_in, const int* in_sizes, int n_in,
                              void* d_out, int out_size, void* d_ws, size_t ws_size,
                              hipStream_t stream) {
    const float* I = (const float*)d_in[0];
    float* out = (float*)d_out;
    dim3 grid(16, 96);   // 16 workgroups x 4 waves = 64 block-rows per plane; 96 planes
    sas_fused<<<grid, dim3(256), 0, stream>>>(I, out);
}

// Round 3
// 281.673 us; speedup vs baseline: 1.1556x; 1.1556x over previous
//
#include <hip/hip_runtime.h>

#define HW 512
#define RA 0.35355339059327373f
#define RB 0.25f

__device__ __forceinline__ int reflect512(int v) {
    v = v < 0 ? -v : v;
    v = v > 511 ? 1022 - v : v;
    return v;
}

__device__ __forceinline__ float softt2(float x) {
    // soft-threshold at lambda=0.1 (operates on 2x-scaled Haar values)
    return copysignf(fmaxf(fabsf(x) - 0.1f, 0.0f), x);
}

__device__ __forceinline__ float nlin(float t) {
    float ca = fabsf(t);
    t = (ca < 2.5f) ? t * (ca * 0.4f) : t;
    return fminf(fmaxf(t, -10.0f), 10.0f);
}

// Haar refine with the two 0.5 scales folded into one 0.25 at the end.
// softt(0.5*x) == 0.5*softt2(x) exactly (power-of-2 scaling commutes with rounding,
// and 0.05f is exactly 0.5*0.1f).
__device__ __forceinline__ void haar_quad(float a, float b, float c, float d,
                                          float& oa, float& ob, float& oc, float& od) {
    float s1 = a + b, s2 = c + d, d1 = a - b, d2 = c - d;
    float LL = s1 + s2, LH = s1 - s2, HL = d1 + d2, HH = d1 - d2;  // 2x scaled
    LH = softt2(LH); HL = softt2(HL); HH = softt2(HH);
    float u1 = LL + LH, u2 = HL + HH, w1 = LL - LH, w2 = HL - HH;
    oa = (u1 + u2) * 0.25f; ob = (u1 - u2) * 0.25f;
    oc = (w1 + w2) * 0.25f; od = (w1 - w2) * 0.25f;
}

// 8-pt cos-DFT, distinct outputs only (full: [t0,t1,t2,t3,t4,t3,t2,t1])
__device__ __forceinline__ void cos5(const float* __restrict__ x, float* __restrict__ t) {
    float e0 = x[0] + x[4], d0 = x[0] - x[4];
    float e1 = x[2] + x[6];
    float o0 = x[1] + x[5], m0 = x[1] - x[5];
    float o1 = x[3] + x[7], m1 = x[3] - x[7];
    float see = e0 + e1, dee = e0 - e1, soo = o0 + o1, dd = m0 - m1;
    t[0] = RA * (see + soo);
    t[4] = RA * (see - soo);
    t[2] = RA * dee;
    float a = RA * d0, b = RB * dd;
    t[1] = a + b;
    t[3] = a - b;
}

// 8-pt sin-DFT, distinct outputs only (full: [0,s0,s1,s2,0,-s2,-s1,-s0])
__device__ __forceinline__ void sin3(const float* __restrict__ x, float* __restrict__ s) {
    float d1 = x[2] - x[6];
    float m0 = x[1] - x[5];
    float o0 = x[1] + x[5];
    float o1 = x[3] + x[7], m1 = x[3] - x[7];
    float qq = m0 + m1;
    float a = RB * qq, b = RA * d1;
    s[0] = a + b;
    s[1] = RA * (o0 - o1);
    s[2] = a - b;
}

// cos-DFT of a symmetric 8-vector [x0,x1,x2,x3,x4,x3,x2,x1] (exact specialization)
__device__ __forceinline__ void cos5_sym(const float* __restrict__ x, float* __restrict__ t) {
    float e0 = x[0] + x[4], d0 = x[0] - x[4];
    float tx2 = 2.0f * x[2];
    float see = e0 + tx2, dee = e0 - tx2;
    float soo = 2.0f * (x[1] + x[3]);
    float m0 = x[1] - x[3];
    t[0] = RA * (see + soo);
    t[4] = RA * (see - soo);
    t[2] = RA * dee;
    float a = RA * d0, b = 0.5f * m0;   // RB * (2*m0)
    t[1] = a + b;
    t[3] = a - b;
}

// sin-DFT of an antisymmetric 8-vector [0,y0,y1,y2,0,-y2,-y1,-y0] (exact specialization)
__device__ __forceinline__ void sin3_asym(const float* __restrict__ y, float* __restrict__ s) {
    float a = 0.5f * (y[0] + y[2]);          // RB * (2*(y0+y2))
    float b = (2.0f * RA) * y[1];            // RA * (2*y1)
    s[0] = a + b;
    s[1] = (2.0f * RA) * (y[0] - y[2]);
    s[2] = a - b;
}

__launch_bounds__(256, 3)
__global__ void sas_fused(const float* __restrict__ in, float* __restrict__ out) {
    const int lane = threadIdx.x & 63;   // block-col 0..63
    const int wv = threadIdx.x >> 6;     // wave in workgroup
    const int p = blockIdx.y;            // plane (b*3+c)
    const int by = blockIdx.x * 4 + wv;  // block-row 0..63
    const float* __restrict__ inP = in + (size_t)p * (HW * HW);
    const int cx = lane * 8;

    const float e = 0.45783336f;                  // exp(-1/1.28)
    const float inv_s = 1.0f / ((1.0f + 2.0f * e) * (1.0f + 2.0f * e));

    // ---- issue ALL 10 row-loads upfront (20 dwordx4 in flight -> latency pipelined) ----
    float4 va[10], vb[10];
#pragma unroll
    for (int j = 0; j < 10; ++j) {
        int gy = reflect512(by * 8 - 1 + j);
        const float* r = inP + (size_t)gy * HW + cx;
        va[j] = *(const float4*)r;
        vb[j] = *(const float4*)(r + 4);
    }

    // ---- horizontal gaussian pass per row (consumes va/vb progressively) ----
    float h[10][8];
#pragma unroll
    for (int j = 0; j < 10; ++j) {
        float lft = __shfl_up(vb[j].w, 1);    // neighbor's col 7
        float rgt = __shfl_down(va[j].x, 1);  // neighbor's col 0
        if (lane == 0)  lft = va[j].y;        // reflect(-1) = col 1
        if (lane == 63) rgt = vb[j].z;        // reflect(512) = col 510
        float xr[10] = {lft, va[j].x, va[j].y, va[j].z, va[j].w,
                        vb[j].x, vb[j].y, vb[j].z, vb[j].w, rgt};
#pragma unroll
        for (int c = 0; c < 8; ++c)
            h[j][c] = e * (xr[c] + xr[c + 2]) + xr[c + 1];
    }

    // ---- vertical gaussian pass ----
    float B[8][8];
#pragma unroll
    for (int j = 0; j < 8; ++j)
#pragma unroll
        for (int c = 0; c < 8; ++c)
            B[j][c] = (e * (h[j][c] + h[j + 2][c]) + h[j + 1][c]) * inv_s;

    // ---- forward row pass: per row keep 5 cos + 3 sin distinct values (transposed) ----
    float cpT[5][8], spT[3][8];
#pragma unroll
    for (int m = 0; m < 8; ++m) {
        float t[5], s[3];
        cos5(B[m], t);
        sin3(B[m], s);
#pragma unroll
        for (int v = 0; v < 5; ++v) cpT[v][m] = t[v];
#pragma unroll
        for (int v = 0; v < 3; ++v) spT[v][m] = s[v];
    }

    // ---- forward column pass -> 34 distinct T values ----
    // T[u][v] = cosDFT(P col v)[u] - sinDFT(Q col v)[u]; cols 5..7 mirror 3..1 with +sin.
    float Tc0[5], Tc4[5];            // T[:,0], T[:,4] (u-symmetric, 5 distinct each)
    cos5(cpT[0], Tc0);
    cos5(cpT[4], Tc4);
    float Tt[3], Tb[3], TA[3][3], TB[3][3];  // per v=1..3: u=0, u=4, u=1..3 (-sin), u=1..3 (+sin)
#pragma unroll
    for (int vi = 0; vi < 3; ++vi) {
        float t[5], s[3];
        cos5(cpT[vi + 1], t);
        sin3(spT[vi], s);
        Tt[vi] = t[0];
        Tb[vi] = t[4];
#pragma unroll
        for (int ui = 0; ui < 3; ++ui) {
            TA[vi][ui] = t[ui + 1] - s[ui];
            TB[vi][ui] = t[ui + 1] + s[ui];
        }
    }

    // ---- nonlinearity on the 34 distinct values (duplicates stay exactly equal) ----
#pragma unroll
    for (int i = 0; i < 5; ++i) { Tc0[i] = nlin(Tc0[i]); Tc4[i] = nlin(Tc4[i]); }
#pragma unroll
    for (int vi = 0; vi < 3; ++vi) {
        Tt[vi] = nlin(Tt[vi]);
        Tb[vi] = nlin(Tb[vi]);
#pragma unroll
        for (int ui = 0; ui < 3; ++ui) {
            TA[vi][ui] = nlin(TA[vi][ui]);
            TB[vi][ui] = nlin(TB[vi][ui]);
        }
    }

    // ---- inverse row pass: rows 0,4 are symmetric; rows 5..7 mirror 3..1 ----
    float p2[5][5], q2[3][3];
    {
        float x0[5] = {Tc0[0], Tt[0], Tt[1], Tt[2], Tc4[0]};
        cos5_sym(x0, p2[0]);
        float x4[5] = {Tc0[4], Tb[0], Tb[1], Tb[2], Tc4[4]};
        cos5_sym(x4, p2[4]);
    }
#pragma unroll
    for (int u = 1; u <= 3; ++u) {
        float r8[8] = {Tc0[u], TA[0][u - 1], TA[1][u - 1], TA[2][u - 1], Tc4[u],
                       TB[2][u - 1], TB[1][u - 1], TB[0][u - 1]};
        cos5(r8, p2[u]);
        sin3(r8, q2[u - 1]);
    }

    // ---- inverse column pass: p2 cols symmetric, q2 cols antisymmetric ----
    float Rc0[5], Rc4[5];
    {
        float c0[5] = {p2[0][0], p2[1][0], p2[2][0], p2[3][0], p2[4][0]};
        cos5_sym(c0, Rc0);
        float c4[5] = {p2[0][4], p2[1][4], p2[2][4], p2[3][4], p2[4][4]};
        cos5_sym(c4, Rc4);
    }
    float r0v[3], r4v[3], RAm[3][3], RBm[3][3];
#pragma unroll
    for (int vi = 0; vi < 3; ++vi) {
        int v = vi + 1;
        float cs[5] = {p2[0][v], p2[1][v], p2[2][v], p2[3][v], p2[4][v]};
        float t[5];
        cos5_sym(cs, t);
        float y[3] = {q2[0][vi], q2[1][vi], q2[2][vi]};
        float s[3];
        sin3_asym(y, s);
        r0v[vi] = t[0];
        r4v[vi] = t[4];
#pragma unroll
        for (int ui = 0; ui < 3; ++ui) {
            RAm[vi][ui] = t[ui + 1] - s[ui];
            RBm[vi][ui] = t[ui + 1] + s[ui];
        }
    }

    // ---- expand rec (centro-symmetric) from 34 distinct values (register renames) ----
    float rec[8][8];
#pragma unroll
    for (int u = 0; u < 8; ++u) {
        int us = (u <= 4) ? u : 8 - u;
        rec[u][0] = Rc0[us];
        rec[u][4] = Rc4[us];
    }
#pragma unroll
    for (int v = 1; v < 8; ++v) {
        if (v == 4) continue;
        int vs = (v <= 4) ? v : 8 - v;
        bool vf = v > 4;
        rec[0][v] = r0v[vs - 1];
        rec[4][v] = r4v[vs - 1];
#pragma unroll
        for (int u = 1; u < 8; ++u) {
            if (u == 4) continue;
            int us = (u <= 4) ? u : 8 - u;
            bool uf = u > 4;
            rec[u][v] = (vf != uf) ? RBm[vs - 1][us - 1] : RAm[vs - 1][us - 1];
        }
    }

    // ---- residual + Haar refine on both streams + coalesced (cached) stores ----
    const int chId = (p / 3) * 6 + (p % 3);
    float* __restrict__ oI = out + ((size_t)chId << 18);
    float* __restrict__ oR = out + ((size_t)(chId + 3) << 18);
#pragma unroll
    for (int qy = 0; qy < 4; ++qy) {
        float ti[2][8], tr_[2][8];
#pragma unroll
        for (int qx = 0; qx < 4; ++qx) {
            float d00 = rec[2 * qy][2 * qx],     d01 = rec[2 * qy][2 * qx + 1];
            float d10 = rec[2 * qy + 1][2 * qx], d11 = rec[2 * qy + 1][2 * qx + 1];
            haar_quad(d00, d01, d10, d11,
                      ti[0][2 * qx], ti[0][2 * qx + 1], ti[1][2 * qx], ti[1][2 * qx + 1]);
            float r00 = B[2 * qy][2 * qx]     - d00, r01 = B[2 * qy][2 * qx + 1]     - d01;
            float r10 = B[2 * qy + 1][2 * qx] - d10, r11 = B[2 * qy + 1][2 * qx + 1] - d11;
            haar_quad(r00, r01, r10, r11,
                      tr_[0][2 * qx], tr_[0][2 * qx + 1], tr_[1][2 * qx], tr_[1][2 * qx + 1]);
        }
        size_t base = (size_t)(by * 8 + 2 * qy) * HW + cx;
        *(float4*)&oI[base]          = make_float4(ti[0][0], ti[0][1], ti[0][2], ti[0][3]);
        *(float4*)&oI[base + 4]      = make_float4(ti[0][4], ti[0][5], ti[0][6], ti[0][7]);
        *(float4*)&oI[base + HW]     = make_float4(ti[1][0], ti[1][1], ti[1][2], ti[1][3]);
        *(float4*)&oI[base + HW + 4] = make_float4(ti[1][4], ti[1][5], ti[1][6], ti[1][7]);
        *(float4*)&oR[base]          = make_float4(tr_[0][0], tr_[0][1], tr_[0][2], tr_[0][3]);
        *(float4*)&oR[base + 4]      = make_float4(tr_[0][4], tr_[0][5], tr_[0][6], tr_[0][7]);
        *(float4*)&oR[base + HW]     = make_float4(tr_[1][0], tr_[1][1], tr_[1][2], tr_[1][3]);
        *(float4*)&oR[base + HW + 4] = make_float4(tr_[1][4], tr_[1][5], tr_[1][6], tr_[1][7]);
    }
}

extern "C" void kernel_launch(void* const* d_in, const int* in_sizes, int n_in,
                              void* d_out, int out_size, void* d_ws, size_t ws_size,
                              hipStream_t stream) {
    const float* I = (const float*)d_in[0];
    float* out = (float*)d_out;
    dim3 grid(16, 96);   // 16 workgroups x 4 waves = 64 block-rows per plane; 96 planes
    sas_fused<<<grid, dim3(256), 0, stream>>>(I, out);
}